// Round 12
// baseline (304.269 us; speedup 1.0000x reference)
//
#include <hip/hip_runtime.h>
#include <cstddef>

#define NN 1024
#define CL 384
#define CP 128
#define NH 8
#define KS 32
#define HK 256

typedef float floatx4 __attribute__((ext_vector_type(4)));
typedef float f32x4 __attribute__((ext_vector_type(4)));
typedef __fp16 f16x8 __attribute__((ext_vector_type(8)));
typedef __fp16 f16x2 __attribute__((ext_vector_type(2)));

union H8 { f16x8 v; f16x2 h[4]; };
union HU { unsigned u; f16x2 h; };

__device__ __forceinline__ float4 ntload4(const float* p) {
    floatx4 t = __builtin_nontemporal_load((const floatx4*)p);
    float4 r; r.x = t.x; r.y = t.y; r.z = t.z; r.w = t.w;
    return r;
}

// ---------------- Kernel 1: LayerNorm + value projection -> f16 pair-packed -
// vp dword[(j>>1)*HK + m] = half2( value[j_even][m], value[j_odd][m] )
__global__ __launch_bounds__(256) void k_ln_value(
    const float* __restrict__ local_, const float* __restrict__ ln_scale,
    const float* __restrict__ ln_offset, const float* __restrict__ Wv,
    unsigned* __restrict__ vp)
{
    __shared__ float ln_s[4][CL];
    const int tid = threadIdx.x;
    const int w = tid >> 6, lane = tid & 63;
    const int r = blockIdx.x * 4 + w;
    const float* lp = local_ + (size_t)r * CL;
    float x[6]; float s1 = 0.f, s2 = 0.f;
#pragma unroll
    for (int k = 0; k < 6; ++k) { x[k] = lp[lane + 64*k]; s1 += x[k]; s2 += x[k]*x[k]; }
#pragma unroll
    for (int m = 1; m < 64; m <<= 1) { s1 += __shfl_xor(s1, m); s2 += __shfl_xor(s2, m); }
    const float mean = s1 * (1.f/CL);
    const float var  = fmaxf(s2 * (1.f/CL) - mean*mean, 0.f);
    const float rstd = rsqrtf(var + 1e-5f);
#pragma unroll
    for (int k = 0; k < 6; ++k) {
        const int c = lane + 64*k;
        ln_s[w][c] = (x[k]-mean)*rstd*ln_scale[c] + ln_offset[c];
    }
    __syncthreads();
    const int m_ = tid;
    float acc0=0.f, acc1=0.f, acc2=0.f, acc3=0.f;
    for (int c0 = 0; c0 < CL; c0 += 8) {
        float wv[8];
#pragma unroll
        for (int cc = 0; cc < 8; ++cc) wv[cc] = Wv[(size_t)(c0+cc)*HK + m_];
        {
            const float4 a = *(const float4*)&ln_s[0][c0];
            const float4 b = *(const float4*)&ln_s[0][c0+4];
            acc0 += a.x*wv[0]+a.y*wv[1]+a.z*wv[2]+a.w*wv[3]+b.x*wv[4]+b.y*wv[5]+b.z*wv[6]+b.w*wv[7];
        }
        {
            const float4 a = *(const float4*)&ln_s[1][c0];
            const float4 b = *(const float4*)&ln_s[1][c0+4];
            acc1 += a.x*wv[0]+a.y*wv[1]+a.z*wv[2]+a.w*wv[3]+b.x*wv[4]+b.y*wv[5]+b.z*wv[6]+b.w*wv[7];
        }
        {
            const float4 a = *(const float4*)&ln_s[2][c0];
            const float4 b = *(const float4*)&ln_s[2][c0+4];
            acc2 += a.x*wv[0]+a.y*wv[1]+a.z*wv[2]+a.w*wv[3]+b.x*wv[4]+b.y*wv[5]+b.z*wv[6]+b.w*wv[7];
        }
        {
            const float4 a = *(const float4*)&ln_s[3][c0];
            const float4 b = *(const float4*)&ln_s[3][c0+4];
            acc3 += a.x*wv[0]+a.y*wv[1]+a.z*wv[2]+a.w*wv[3]+b.x*wv[4]+b.y*wv[5]+b.z*wv[6]+b.w*wv[7];
        }
    }
    const int rb2 = blockIdx.x*2;          // row-pair base
    HU pa, pb;
    pa.h = __builtin_amdgcn_cvt_pkrtz(acc0, acc1);
    pb.h = __builtin_amdgcn_cvt_pkrtz(acc2, acc3);
    vp[(size_t)(rb2+0)*HK + m_] = pa.u;
    vp[(size_t)(rb2+1)*HK + m_] = pb.u;
}

// ---------------- Kernel 2: fused attention, MFMA logits, wave-local --------
// Wave owns 256 j. Per 16-row chunk:
//   [vp loads (oldest)] [cvt A(t)->f16] [pair prefetch t+2 (youngest)]
//   [4x mfma_f32_16x16x32_f16] [zf*exp] [PV: shfl p + fdot2] — no barriers.
__global__ __launch_bounds__(256, 3) void k_attn(
    const float* __restrict__ pair, const int* __restrict__ mask,
    const float* __restrict__ Wa, const unsigned* __restrict__ vp,
    const float* __restrict__ Wo, float* __restrict__ outp)
{
    __shared__ float zf[NN];
    __shared__ float sew[4][NH];
    __shared__ float ov4[4][64][4];
    __shared__ float ov[HK];

    const int tid  = threadIdx.x;
    const int w    = tid >> 6;
    const int lane = tid & 63;
    const int n15  = lane & 15;   // MFMA: A-row / D-col(head)
    const int kg   = lane >> 4;   // MFMA: k-group / D-row-group
    const int hq   = lane >> 3;   // PV: head for m = lane*4..+3
    const int i = blockIdx.x;
    const bool bmi = mask[i] != 0;

    for (int k = tid; k < NN; k += 256)
        zf[k] = (bmi && (mask[k] != 0)) ? 1.f : 0.f;

    // B fragments: B[k][n] = Wa[ks*32 + k][n], heads n>=8 zero-padded
    f16x8 bf[4];
#pragma unroll
    for (int ks = 0; ks < 4; ++ks) {
        H8 u;
#pragma unroll
        for (int d = 0; d < 4; ++d) {
            const int k0 = ks*KS + kg*8 + 2*d;
            const float e0 = (n15 < NH) ? Wa[(size_t)k0*NH + n15] : 0.f;
            const float e1 = (n15 < NH) ? Wa[(size_t)(k0+1)*NH + n15] : 0.f;
            u.h[d] = __builtin_amdgcn_cvt_pkrtz(e0, e1);
        }
        bf[ks] = u.v;
    }

    const int jbase = w * 256;
    // A-pattern base: lane holds row (j0 + n15), channels kg*8..+7 (per K-slice)
    const float* abase = pair + (size_t)i*NN*CP + (size_t)n15*CP + kg*8;

    float4 Aa[8], Ab[8];
    auto LOADA = [&](float4* d, int j0) {
#pragma unroll
        for (int ks = 0; ks < 4; ++ks) {
            const float* b = abase + (size_t)j0*CP + ks*KS;
            d[2*ks]   = ntload4(b);
            d[2*ks+1] = ntload4(b + 4);
        }
    };

    float4 ac4; ac4.x = ac4.y = ac4.z = ac4.w = 0.f;
    float se_loc = 0.f;

    LOADA(Aa, jbase);
    LOADA(Ab, jbase + 16);
    __syncthreads();            // zf ready (prologue only)

    auto ITER = [&](float4* BUF, int T) {
        const int j0 = jbase + T*16;
        // 1. value loads (oldest in queue)
        uint4 vv[8];
        {
            const unsigned* vb = vp + (size_t)(j0 >> 1)*HK + lane*4;
#pragma unroll
            for (int pr = 0; pr < 8; ++pr)
                vv[pr] = *(const uint4*)(vb + (size_t)pr*HK);
        }
        // 2. cvt A(T) f32 -> f16 fragments (frees BUF)
        f16x8 fr[4];
#pragma unroll
        for (int ks = 0; ks < 4; ++ks) {
            H8 u;
            u.h[0] = __builtin_amdgcn_cvt_pkrtz(BUF[2*ks].x,   BUF[2*ks].y);
            u.h[1] = __builtin_amdgcn_cvt_pkrtz(BUF[2*ks].z,   BUF[2*ks].w);
            u.h[2] = __builtin_amdgcn_cvt_pkrtz(BUF[2*ks+1].x, BUF[2*ks+1].y);
            u.h[3] = __builtin_amdgcn_cvt_pkrtz(BUF[2*ks+1].z, BUF[2*ks+1].w);
            fr[ks] = u.v;
        }
        // 3. pair prefetch T+2 (youngest; stays in flight through PV)
        if (T + 2 < 16) LOADA(BUF, jbase + (T+2)*16);
        // 4. MFMA logits + masked exp
        f32x4 acc = {0.f, 0.f, 0.f, 0.f};
#pragma unroll
        for (int ks = 0; ks < 4; ++ks)
            acc = __builtin_amdgcn_mfma_f32_16x16x32_f16(fr[ks], bf[ks], acc, 0, 0, 0);
        float pe[4];
#pragma unroll
        for (int r = 0; r < 4; ++r)
            pe[r] = zf[j0 + kg*4 + r] * __expf(acc[r]);
        se_loc += pe[0] + pe[1] + pe[2] + pe[3];     // valid on lanes n15<8 only
        // 5. PV: broadcast p from holder lane, fdot2 with packed f16 value
#pragma unroll
        for (int pr = 0; pr < 8; ++pr) {
            const int src = (pr >> 1)*16 + hq;       // holder of rows 4*(pr>>1)..+3, head hq
            const float p0 = __shfl(pe[2*(pr & 1)],     src);
            const float p1 = __shfl(pe[2*(pr & 1) + 1], src);
            const f16x2 ppk = __builtin_amdgcn_cvt_pkrtz(p0, p1);
            HU d0, d1, d2, d3;
            d0.u = vv[pr].x; d1.u = vv[pr].y; d2.u = vv[pr].z; d3.u = vv[pr].w;
            ac4.x = __builtin_amdgcn_fdot2(ppk, d0.h, ac4.x, false);
            ac4.y = __builtin_amdgcn_fdot2(ppk, d1.h, ac4.y, false);
            ac4.z = __builtin_amdgcn_fdot2(ppk, d2.h, ac4.z, false);
            ac4.w = __builtin_amdgcn_fdot2(ppk, d3.h, ac4.w, false);
        }
    };

    for (int t = 0; t < 16; t += 2) {
        ITER(Aa, t);
        ITER(Ab, t + 1);
    }

    // ---- epilogue: combine 4 waves ----
    {
        float se_t = se_loc;
        se_t += __shfl_xor(se_t, 16);    // partners share n15 -> sums kg groups
        se_t += __shfl_xor(se_t, 32);
        if (lane < NH) sew[w][lane] = se_t;
    }
    ov4[w][lane][0] = ac4.x; ov4[w][lane][1] = ac4.y;
    ov4[w][lane][2] = ac4.z; ov4[w][lane][3] = ac4.w;
    __syncthreads();

    {   // combine, normalize
        const int m = tid;               // 0..255
        const float s4 = ov4[0][m>>2][m&3] + ov4[1][m>>2][m&3]
                       + ov4[2][m>>2][m&3] + ov4[3][m>>2][m&3];
        const int h = m >> 5;
        const float se = sew[0][h] + sew[1][h] + sew[2][h] + sew[3][h];
        const float inv = (se > 0.f) ? (1.f/se) : 0.f;
        ov[m] = s4 * inv;
    }
    __syncthreads();

    // ---- final projection out = ov @ W_out ----
    for (int o = tid; o < CL; o += 256) {
        float a0 = 0.f;
        for (int m = 0; m < HK; m += 4) {
            const float4 x0 = *(const float4*)&ov[m];
            a0 += x0.x*Wo[(size_t)(m+0)*CL + o] + x0.y*Wo[(size_t)(m+1)*CL + o]
                + x0.z*Wo[(size_t)(m+2)*CL + o] + x0.w*Wo[(size_t)(m+3)*CL + o];
        }
        outp[(size_t)i*CL + o] = a0;
    }
}

extern "C" void kernel_launch(void* const* d_in, const int* in_sizes, int n_in,
                              void* d_out, int out_size, void* d_ws, size_t ws_size,
                              hipStream_t stream)
{
    (void)in_sizes; (void)n_in; (void)out_size; (void)ws_size;
    const float* local_ = (const float*)d_in[0];
    const float* pair   = (const float*)d_in[1];
    const int*   mask   = (const int*)d_in[2];
    const float* scale  = (const float*)d_in[3];
    const float* offset = (const float*)d_in[4];
    const float* Wv     = (const float*)d_in[5];
    const float* Wa     = (const float*)d_in[6];
    const float* Wo     = (const float*)d_in[7];
    unsigned* vp = (unsigned*)d_ws;       // 512 KiB: f16 row-pair-packed value
    k_ln_value<<<NN/4, 256, 0, stream>>>(local_, scale, offset, Wv, vp);
    k_attn<<<NN, 256, 0, stream>>>(pair, mask, Wa, vp, Wo, (float*)d_out);
}